// Round 17
// baseline (621.669 us; speedup 1.0000x reference)
//
#include <hip/hip_runtime.h>
#include <hip/hip_bf16.h>

// ---------------- problem constants ----------------
#define B_  16
#define S_  5
#define W_  12
#define NL_ 49
#define H_  1024
#define V_  15000
#define SEQ_N   14400000          // B*S*W*V
#define STOP_N  80
#define OUT_STOP (SEQ_N)
#define OUT_SCORE (SEQ_N + STOP_N)

typedef __attribute__((ext_vector_type(8))) short     short8;
typedef __attribute__((ext_vector_type(4))) float     f32x4;
typedef __attribute__((ext_vector_type(4))) unsigned int u32x4;
typedef __attribute__((ext_vector_type(4))) unsigned short us4;

// ---------------- ws layout (bytes) ----------------
#define OFF_FCWT   0ull            // 15000x1024 bf16
#define OFF_WWHHP  30720000ull     // 4096x1024 bf16 (gate-permuted)
#define OFF_WWIHP  39108608ull     // 4096x1024 bf16 (gate-permuted)
#define OFF_WSCATP 47497216ull     // 4096x2048 bf16 (gate-permuted, wih|whh)
#define OFF_W1AT   64274432ull     // 1024x1024 bf16
#define OFF_W1BT   66371584ull     // 1024x1024 bf16
#define OFF_FBF    68468736ull     // 784x1024 bf16
#define OFF_XIN    70074368ull     // 960x1024 bf16
#define OFF_PF     72040448ull     // 784x1024 f32
#define OFF_XW     75251712ull     // 960x4096 f32 (cols gate-permuted)
#define OFF_HBALL  90980352ull     // 960x1024 bf16
#define OFF_HWBF0  92946432ull     // 80x1024 bf16
#define OFF_HWBF1  93110272ull     // 80x1024 bf16
#define OFF_ACAT1  93274112ull     // 16x2048 bf16
#define OFF_H      93339648ull     // 16x1024 f32
#define OFF_EVAL   93405184ull     // 784 f32
#define OFF_ACAT0  93408384ull     // 16x2048 bf16   -- zero region start (524288B)
#define OFF_C      93473920ull     // 16x1024 f32
#define OFF_CW     93539456ull     // 80x1024 f32
#define OFF_HPROJ  93867136ull     // 16x1024 f32
#define OFF_BAR    93932672ull     // 4KB barrier page (zeroed by prep)
#define WS_TOTAL   93936768ull
#define ZERO_BASE  OFF_ACAT0

// ---------------- helpers ----------------
__device__ __forceinline__ unsigned short f2bf(float x){
  unsigned u = __float_as_uint(x);
  u += 0x7fffu + ((u >> 16) & 1u);
  return (unsigned short)(u >> 16);
}
__device__ __forceinline__ float sigm(float x){ return 1.f/(1.f+expf(-x)); }

typedef __attribute__((address_space(3))) unsigned int  as3_u32;
typedef __attribute__((address_space(1))) const unsigned int as1_u32;

__device__ __forceinline__ void gl16(const void* g, void* l){
  __builtin_amdgcn_global_load_lds((as1_u32*)g, (as3_u32*)l, 16, 0, 0);
}

// Stage ROWS x (CH*8) bf16 tile into LDS via global_load_lds, XOR-swizzled SOURCE
// so LDS slot [r][cb'] holds global chunk cb'^(r&7).
template<int ROWS,int CH,int NW>
__device__ __forceinline__ void stage_swz(const unsigned short* __restrict__ gbase, int grs,
                                          unsigned short* lds, int wid, int lane,
                                          int r0, int rmax){
  constexpr int RPI = 64/CH;
  constexpr int NISS = ROWS/RPI;
  const int r_in = lane / CH;
  const int cbp  = lane % CH;
  #pragma unroll
  for (int it = wid; it < NISS; it += NW){
    int rl = it*RPI + r_in;
    int gr = r0 + rl; gr = gr < rmax ? gr : rmax-1;
    int cb = cbp ^ (rl & 7);
    gl16(gbase + (size_t)gr*grs + cb*8, lds + it*RPI*CH*8);
  }
}

// ---------------- coalesced 64x64 f32->bf16 transpose tile ----------------
__device__ __forceinline__ void transp64(const float* __restrict__ src, int sld,
                                         int rb, int cb, int Cc,
                                         unsigned short* __restrict__ dst, int dld,
                                         float (*t)[65])
{
  const int tx = threadIdx.x & 15, ty = threadIdx.x >> 4;
  #pragma unroll
  for (int ii = 0; ii < 4; ii++){
    int r = ty + ii*16;
    int c = cb + tx*4;
    const float* s = src + (size_t)(rb + r)*sld + c;
    f32x4 v;
    if (c + 4 <= Cc) v = *(const f32x4*)s;
    else {
      v[0] = (c   < Cc) ? s[0] : 0.f;
      v[1] = (c+1 < Cc) ? s[1] : 0.f;
      v[2] = (c+2 < Cc) ? s[2] : 0.f;
      v[3] = (c+3 < Cc) ? s[3] : 0.f;
    }
    t[r][tx*4+0]=v[0]; t[r][tx*4+1]=v[1]; t[r][tx*4+2]=v[2]; t[r][tx*4+3]=v[3];
  }
  __syncthreads();
  #pragma unroll
  for (int ii = 0; ii < 4; ii++){
    int c = ty + ii*16;
    if (cb + c < Cc){
      int r4 = tx*4;
      us4 o; o[0]=f2bf(t[r4][c]); o[1]=f2bf(t[r4+1][c]); o[2]=f2bf(t[r4+2][c]); o[3]=f2bf(t[r4+3][c]);
      *(us4*)(dst + (size_t)(cb + c)*dld + rb + r4) = o;
    }
  }
}

// ---------------- mega-prep (grid-stride) ----------------
#define U0 200704u                 // features units (784*256)
#define U1 (U0+1048576u)           // w_whh
#define U2 (U1+1048576u)           // w_wih
#define U3 (U2+1048576u)           // s_wih
#define U4 (U3+1048576u)           // s_whh
#define U5 (U4+245760u)            // gather  (total units)
#define NCVT_BLK 1280
#define NTR_BLK  2136              // x2 tiles = 4272 = 512 attn + 3760 fc
#define NZ_BLK   16
#define NPREP    (NCVT_BLK + NTR_BLK + NZ_BLK)

__device__ __forceinline__ void cvt_gate_unit(const float* __restrict__ src,
                                              unsigned short* __restrict__ dst,
                                              unsigned e, int dld, int doff){
  int n = e >> 8, cc = (e & 255)*4;
  int gate = (n >> 4) & 3, j = ((n >> 6) << 4) | (n & 15);
  f32x4 v = *(const f32x4*)(src + ((size_t)(gate*1024 + j) << 10) + cc);
  us4 o; o[0]=f2bf(v[0]); o[1]=f2bf(v[1]); o[2]=f2bf(v[2]); o[3]=f2bf(v[3]);
  *(us4*)(dst + (size_t)n*dld + doff + cc) = o;
}

__global__ void k_prep(const float* __restrict__ features,
                       const float* __restrict__ w_whh, const float* __restrict__ w_wih,
                       const float* __restrict__ s_wih, const float* __restrict__ s_whh,
                       const float* __restrict__ emb, const int* __restrict__ reports,
                       const float* __restrict__ attn_w1, const float* __restrict__ fc_w,
                       unsigned short* __restrict__ FBF, unsigned short* __restrict__ WWHHP,
                       unsigned short* __restrict__ WWIHP, unsigned short* __restrict__ WSCATP,
                       unsigned short* __restrict__ XIN,
                       unsigned short* __restrict__ W1AT, unsigned short* __restrict__ W1BT,
                       unsigned short* __restrict__ FCWT, char* __restrict__ zbase)
{
  __shared__ float t[64][65];
  int bx = blockIdx.x;
  if (bx < NCVT_BLK){
    for (unsigned u = bx*256u + threadIdx.x; u < U5; u += NCVT_BLK*256u){
      if (u < U0){
        int idx = u*4;
        f32x4 v = *(const f32x4*)(features + idx);
        us4 o; o[0]=f2bf(v[0]); o[1]=f2bf(v[1]); o[2]=f2bf(v[2]); o[3]=f2bf(v[3]);
        *(us4*)(FBF + idx) = o;
      } else if (u < U1){
        cvt_gate_unit(w_whh, WWHHP, u - U0, 1024, 0);
      } else if (u < U2){
        cvt_gate_unit(w_wih, WWIHP, u - U1, 1024, 0);
      } else if (u < U3){
        cvt_gate_unit(s_wih, WSCATP, u - U2, 2048, 0);
      } else if (u < U4){
        cvt_gate_unit(s_whh, WSCATP, u - U3, 2048, 1024);
      } else {
        unsigned e = u - U4;
        int m = e >> 8, k = (e & 255)*4;
        int w = m / 80, r = m % 80, s = r >> 4, b = r & 15;
        int tok = (w == 0) ? 1 : reports[b*60 + s*12 + (w-1)];
        f32x4 v = *(const f32x4*)(emb + ((size_t)tok << 10) + k);
        us4 o; o[0]=f2bf(v[0]); o[1]=f2bf(v[1]); o[2]=f2bf(v[2]); o[3]=f2bf(v[3]);
        *(us4*)(XIN + (size_t)m*1024 + k) = o;
      }
    }
  } else if (bx < NCVT_BLK + NTR_BLK){
    int base = (bx - NCVT_BLK)*2;
    #pragma unroll
    for (int bt = 0; bt < 2; bt++){
      if (bt) __syncthreads();
      int tile = base + bt;
      if (tile < 512){
        int z = tile >> 8, rem = tile & 255;
        int rb = (rem & 15)*64, cb = (rem >> 4)*64;
        transp64(attn_w1 + (size_t)z*1024*1024, 1024, rb, cb, 1024, z ? W1BT : W1AT, 1024, t);
      } else {
        int ft = tile - 512;
        int rb = (ft & 15)*64, cb = (ft >> 4)*64;
        transp64(fc_w, V_, rb, cb, V_, FCWT, 1024, t);
      }
    }
  } else {
    int idx = bx - (NCVT_BLK + NTR_BLK);
    #pragma unroll
    for (int it = 0; it < 8; it++){
      size_t off = ((size_t)(idx + it*NZ_BLK))*4096 + threadIdx.x*16;
      *(u32x4*)(zbase + off) = (u32x4){0u,0u,0u,0u};
    }
    if (idx == 0)   // barrier page
      *(u32x4*)(zbase + 524288 + threadIdx.x*16) = (u32x4){0u,0u,0u,0u};
  }
}

// ---------------- GEMM core (LDS pointers passed in) ----------------
// EPI: 0 plain, 1 +bias, 2 +bias & scatter rows to seq output (nt), 3 plain nt
template<int BM,int BN,int BK,int WM,int WN,int EPI>
__device__ __forceinline__ void gemm_core(
    unsigned short* As, unsigned short* Bs,
    const unsigned short* __restrict__ A, int lda,
    const unsigned short* __restrict__ Bt, int ldb,
    float* __restrict__ C, int ldc,
    const float* __restrict__ bias,
    int M, int N, int K, int n0, int m0)
{
  constexpr int NWV = WM*WN;
  constexpr int CH = BK/8;
  const int tid  = threadIdx.x;
  const int lane = tid & 63;
  const int wave = tid >> 6;
  constexpr int WROWS = BM/WM, WCOLS = BN/WN;
  constexpr int FM = WROWS/16, FN = WCOLS/16;
  const int wm = wave / WN, wn = wave % WN;
  const int g = lane >> 4, fr = lane & 15;
  const int sx = fr & 7;

  f32x4 acc[FM][FN];
  #pragma unroll
  for (int a=0;a<FM;a++)
    #pragma unroll
    for (int b=0;b<FN;b++) acc[a][b] = (f32x4){0.f,0.f,0.f,0.f};

  for (int k0 = 0; k0 < K; k0 += BK) {
    if (k0) __syncthreads();
    stage_swz<BM,CH,NWV>(A + k0, lda, As, wave, lane, m0, M);
    stage_swz<BN,CH,NWV>(Bt + k0, ldb, Bs, wave, lane, n0, N);
    __syncthreads();
    #pragma unroll
    for (int kk = 0; kk < BK; kk += 32) {
      const int so = ((kk/8 + g) ^ sx) * 8;
      short8 af[FM], bt[FN];
      #pragma unroll
      for (int fm=0; fm<FM; fm++)
        af[fm] = *(const short8*)(As + (wm*WROWS + fm*16 + fr)*BK + so);
      #pragma unroll
      for (int fn=0; fn<FN; fn++)
        bt[fn] = *(const short8*)(Bs + (wn*WCOLS + fn*16 + fr)*BK + so);
      #pragma unroll
      for (int fm=0; fm<FM; fm++)
        #pragma unroll
        for (int fn=0; fn<FN; fn++)
          acc[fm][fn] = __builtin_amdgcn_mfma_f32_16x16x32_bf16(af[fm], bt[fn], acc[fm][fn], 0, 0, 0);
    }
  }

  #pragma unroll
  for (int fm=0; fm<FM; fm++)
    #pragma unroll
    for (int fn=0; fn<FN; fn++)
      #pragma unroll
      for (int j=0; j<4; j++){
        int m = m0 + wm*WROWS + fm*16 + g*4 + j;
        int n = n0 + wn*WCOLS + fn*16 + fr;
        if (m < M && n < N) {
          float v = acc[fm][fn][j];
          if (EPI == 1 || EPI == 2) v += bias[n];
          if (EPI == 2) {
            int b = m & 15, s = (m >> 4) % 5, w = m / 80;
            __builtin_nontemporal_store(v, &C[(size_t)((b*5 + s)*12 + w)*V_ + n]);
          } else if (EPI == 3) {
            __builtin_nontemporal_store(v, &C[(size_t)m*ldc + n]);
          } else {
            C[(size_t)m*ldc + n] = v;
          }
        }
      }
}

// standalone GEMM (static LDS)
template<int BM,int BN,int BK,int WM,int WN,int EPI>
__global__ void k_gemm(const unsigned short* __restrict__ A, int lda,
                       const unsigned short* __restrict__ Bt, int ldb,
                       float* __restrict__ C, int ldc,
                       const float* __restrict__ bias,
                       int M, int N, int K)
{
  __shared__ __align__(16) unsigned short As[BM*BK];
  __shared__ __align__(16) unsigned short Bs[BN*BK];
  const int n0 = blockIdx.x * BN, m0 = blockIdx.y * BM;
  if (n0 >= N) return;
  gemm_core<BM,BN,BK,WM,WN,EPI>(As, Bs, A, lda, Bt, ldb, C, ldc, bias, M, N, K, n0, m0);
}

// fused PF + XW GEMMs (independent) in one dispatch; 48KB dynamic LDS (union)
__global__ void __launch_bounds__(256) k_pf_xw(
    const unsigned short* __restrict__ FBF, const unsigned short* __restrict__ W1AT,
    float* __restrict__ PF, const float* __restrict__ attn_b1,
    const unsigned short* __restrict__ XIN, const unsigned short* __restrict__ WWIHP,
    float* __restrict__ XW)
{
  extern __shared__ __align__(16) unsigned short smem[];
  unsigned short* As = smem;
  unsigned short* Bs = smem + 64*128;       // 16KB for As (both variants)
  int bx = blockIdx.x;
  if (bx < 208){
    int n0 = (bx & 15)*64, m0 = (bx >> 4)*64;
    gemm_core<64,64,128,2,2,1>(As, Bs, FBF,1024, W1AT,1024, PF,1024, attn_b1,
                               784,1024,1024, n0, m0);
  } else {
    int t = bx - 208;
    int n0 = (t & 31)*128, m0 = (t >> 5)*64;
    gemm_core<64,128,128,2,2,3>(As, Bs, XIN,1024, WWIHP,1024, XW,4096, nullptr,
                                960,4096,1024, n0, m0);
  }
}

// ---------------- gate GEMM fused with LSTM cell (single-buffer, BK templated) ----------------
template<int BM,int BN,int BK,int WN,int SENT>
__global__ void k_gemm_cell(const unsigned short* __restrict__ A, int lda,
                            const unsigned short* __restrict__ Bt, int ldb,
                            const float* __restrict__ Xg, int ldx,
                            const float* __restrict__ bih, const float* __restrict__ bhh,
                            float* __restrict__ cst,
                            unsigned short* __restrict__ h1, int ldh1,
                            unsigned short* __restrict__ h2,
                            float* __restrict__ hf,
                            int M, int K)
{
  constexpr int CH = BK/8;
  __shared__ __align__(16) unsigned short As[BM*BK];
  __shared__ __align__(16) unsigned short Bs[BN*BK];
  const int tid  = threadIdx.x;
  const int lane = tid & 63;
  const int wn   = tid >> 6;
  const int n0 = blockIdx.x * BN, m0 = blockIdx.y * BM;
  const int g = lane >> 4, fr = lane & 15;
  const int sx = fr & 7;

  f32x4 acc[4];
  #pragma unroll
  for (int b=0;b<4;b++) acc[b] = (f32x4){0.f,0.f,0.f,0.f};

  for (int k0 = 0; k0 < K; k0 += BK) {
    if (k0) __syncthreads();
    stage_swz<BM,CH,WN>(A + k0, lda, As, wn, lane, m0, M);
    stage_swz<BN,CH,WN>(Bt + k0, ldb, Bs, wn, lane, n0, 4096);
    __syncthreads();
    #pragma unroll
    for (int kk = 0; kk < BK; kk += 32) {
      const int so = ((kk/8 + g) ^ sx) * 8;
      short8 af = *(const short8*)(As + fr*BK + so);
      #pragma unroll
      for (int fn=0; fn<4; fn++){
        short8 bt = *(const short8*)(Bs + (wn*64 + fn*16 + fr)*BK + so);
        acc[fn] = __builtin_amdgcn_mfma_f32_16x16x32_bf16(af, bt, acc[fn], 0, 0, 0);
      }
    }
  }

  const int nb = n0 + wn*64 + fr;       // column of gate 0 (permuted layout)
  const int j  = ((n0 + wn*64) >> 2) + fr;
  const float b0 = bih[j]        + bhh[j];
  const float b1 = bih[1024 + j] + bhh[1024 + j];
  const float b2 = bih[2048 + j] + bhh[2048 + j];
  const float b3 = bih[3072 + j] + bhh[3072 + j];
  #pragma unroll
  for (int jj=0; jj<4; jj++){
    int m = m0 + g*4 + jj;
    if (m < M){
      float gi = acc[0][jj] + b0;
      float gf = acc[1][jj] + b1;
      float gg = acc[2][jj] + b2;
      float go = acc[3][jj] + b3;
      if (!SENT){
        const float* xg = Xg + (size_t)m*ldx + nb;
        gi += xg[0]; gf += xg[16]; gg += xg[32]; go += xg[48];
      }
      float cn = sigm(gf)*cst[m*1024 + j] + sigm(gi)*tanhf(gg);
      float hn = sigm(go)*tanhf(cn);
      cst[m*1024 + j] = cn;
      unsigned short hb = f2bf(hn);
      h1[(size_t)m*ldh1 + j] = hb;
      h2[(size_t)m*1024 + j] = hb;
      if (SENT) hf[m*1024 + j] = hn;
    }
  }
}

// ---------------- persistent word chain: 12 steps, load-polling barrier ----------------
// 160 blocks x 128 threads, 72KB LDS -> all co-resident (160 <= 256 CUs).
// Barrier: monotonic arrival counter bar[0] (one atomicAdd per block/step);
// last arriver stores release flag bar[1]=w+1; others poll bar[1] with relaxed
// acquire LOADS (no RMW -> no atomic-unit serialization, fixes R5's pathology).
__global__ void __launch_bounds__(128) k_word_chain(
    const unsigned short* __restrict__ Bt,   // WWHHP [4096,1024]
    const float* __restrict__ XW,            // [960,4096] (cols permuted)
    const float* __restrict__ bih, const float* __restrict__ bhh,
    float* __restrict__ cw,                  // [80,1024]
    unsigned short* __restrict__ HW0, unsigned short* __restrict__ HW1,
    unsigned short* __restrict__ Hball,      // [960,1024]
    unsigned* __restrict__ bar)
{
  constexpr int BK = 256, CH = BK/8;
  __shared__ __align__(16) unsigned short As[16*BK];
  __shared__ __align__(16) unsigned short Bs[128*BK];
  const int tid = threadIdx.x, lane = tid & 63, wn = tid >> 6;
  const int n0 = blockIdx.x * 128, m0 = blockIdx.y * 16;
  const int g = lane >> 4, fr = lane & 15, sx = fr & 7;

  const int nb = n0 + wn*64 + fr;
  const int j  = ((n0 + wn*64) >> 2) + fr;
  const float b0 = bih[j]        + bhh[j];
  const float b1 = bih[1024 + j] + bhh[1024 + j];
  const float b2 = bih[2048 + j] + bhh[2048 + j];
  const float b3 = bih[3072 + j] + bhh[3072 + j];
  unsigned short* HW[2] = {HW0, HW1};

  for (int w = 0; w < W_; w++){
    const unsigned short* A = HW[w & 1];
    f32x4 acc[4];
    #pragma unroll
    for (int b=0;b<4;b++) acc[b] = (f32x4){0.f,0.f,0.f,0.f};
    for (int k0 = 0; k0 < 1024; k0 += BK){
      if (k0) __syncthreads();
      stage_swz<16,CH,2>(A + k0, 1024, As, wn, lane, m0, 80);
      stage_swz<128,CH,2>(Bt + k0, 1024, Bs, wn, lane, n0, 4096);
      __syncthreads();
      #pragma unroll
      for (int kk = 0; kk < BK; kk += 32){
        const int so = ((kk/8 + g) ^ sx) * 8;
        short8 af = *(const short8*)(As + fr*BK + so);
        #pragma unroll
        for (int fn=0; fn<4; fn++){
          short8 bt = *(const short8*)(Bs + (wn*64 + fn*16 + fr)*BK + so);
          acc[fn] = __builtin_amdgcn_mfma_f32_16x16x32_bf16(af, bt, acc[fn], 0, 0, 0);
        }
      }
    }
    unsigned short* hnext = HW[(w + 1) & 1];
    unsigned short* hb_out = Hball + (size_t)w*80*1024;
    const float* xgb = XW + (size_t)(w*80)*4096;
    #pragma unroll
    for (int jj=0; jj<4; jj++){
      int m = m0 + g*4 + jj;
      const float* xg = xgb + (size_t)m*4096 + nb;
      float gi = acc[0][jj] + b0 + xg[0];
      float gf = acc[1][jj] + b1 + xg[16];
      float gg = acc[2][jj] + b2 + xg[32];
      float go = acc[3][jj] + b3 + xg[48];
      float cn = sigm(gf)*cw[m*1024 + j] + sigm(gi)*tanhf(gg);
      float hn = sigm(go)*tanhf(cn);
      cw[m*1024 + j] = cn;
      unsigned short hb = f2bf(hn);
      hnext[(size_t)m*1024 + j] = hb;
      hb_out[(size_t)m*1024 + j] = hb;
    }
    if (w < W_ - 1){
      __syncthreads();
      if (tid == 0){
        __threadfence();
        unsigned old = atomicAdd(&bar[0], 1u);
        if (old == 160u*(unsigned)(w + 1) - 1u){
          __hip_atomic_store(&bar[1], (unsigned)(w + 1), __ATOMIC_RELEASE, __HIP_MEMORY_SCOPE_AGENT);
        } else {
          while (__hip_atomic_load(&bar[1], __ATOMIC_ACQUIRE, __HIP_MEMORY_SCOPE_AGENT) < (unsigned)(w + 1))
            __builtin_amdgcn_s_sleep(2);
        }
        __threadfence();
      }
      __syncthreads();
    }
  }
}

// ---------------- attention (wide): evals then softmax/sum/stop ----------------
__global__ void k_attn_e(const float* __restrict__ PF, const float* __restrict__ hproj,
                         const float* __restrict__ w2, float* __restrict__ evals)
{
  const int bn = blockIdx.x;
  const int b  = bn / NL_;
  const int tid = threadIdx.x;
  __shared__ float red[4];
  const float* pf = PF + ((size_t)bn << 10);
  const float* hp = hproj + (b << 10);
  int k = tid * 4;
  f32x4 a = *(const f32x4*)(pf + k);
  f32x4 hh = *(const f32x4*)(hp + k);
  f32x4 w = *(const f32x4*)(w2 + k);
  float p = tanhf(a[0]+hh[0])*w[0] + tanhf(a[1]+hh[1])*w[1]
          + tanhf(a[2]+hh[2])*w[2] + tanhf(a[3]+hh[3])*w[3];
  #pragma unroll
  for (int o = 32; o; o >>= 1) p += __shfl_down(p, o, 64);
  if ((tid & 63) == 0) red[tid >> 6] = p;
  __syncthreads();
  if (tid == 0) evals[bn] = red[0] + red[1] + red[2] + red[3];
}

template<int INIT>
__global__ void k_attn_fin(const float* __restrict__ evals, const float* __restrict__ features,
                           const float* __restrict__ h, const float* __restrict__ stop_w,
                           const float* __restrict__ stop_b,
                           unsigned short* __restrict__ Acat, float* __restrict__ outp, int s)
{
  const int b = blockIdx.x, tid = threadIdx.x;
  __shared__ float scs[64];
  __shared__ float red[4];
  if (tid < 64){
    float e = (tid < NL_) ? evals[b*NL_ + tid] : -1e30f;
    float mx = e;
    #pragma unroll
    for (int o = 32; o; o >>= 1) mx = fmaxf(mx, __shfl_xor(mx, o, 64));
    float ex = (tid < NL_) ? expf(e - mx) : 0.f;
    float dn = ex;
    #pragma unroll
    for (int o = 32; o; o >>= 1) dn += __shfl_xor(dn, o, 64);
    float sc = ex / dn;
    if (tid < NL_){
      scs[tid] = sc;
      if (!INIT) outp[OUT_SCORE + (b*5 + s)*NL_ + tid] = sc;
    }
  }
  __syncthreads();
  {
    int f0 = tid * 4;
    f32x4 a = (f32x4){0.f,0.f,0.f,0.f};
    const float* fb = features + (((size_t)b*NL_) << 10) + f0;
    #pragma unroll 7
    for (int n = 0; n < NL_; n++){
      f32x4 v = *(const f32x4*)(fb + ((size_t)n << 10));
      float sc = scs[n];
      a[0] += sc*v[0]; a[1] += sc*v[1]; a[2] += sc*v[2]; a[3] += sc*v[3];
    }
    us4 o4; o4[0]=f2bf(a[0]); o4[1]=f2bf(a[1]); o4[2]=f2bf(a[2]); o4[3]=f2bf(a[3]);
    *(us4*)(Acat + b*2048 + f0) = o4;
  }
  if (!INIT){
    int k = tid * 4;
    f32x4 hv = *(const f32x4*)(h + (b << 10) + k);
    f32x4 sw = *(const f32x4*)(stop_w + k);
    float p = hv[0]*sw[0] + hv[1]*sw[1] + hv[2]*sw[2] + hv[3]*sw[3];
    #pragma unroll
    for (int o = 32; o; o >>= 1) p += __shfl_down(p, o, 64);
    if ((tid & 63) == 0) red[tid >> 6] = p;
    __syncthreads();
    if (tid == 0) outp[OUT_STOP + b*5 + s] = sigm(red[0]+red[1]+red[2]+red[3] + stop_b[0]);
  }
}

// ---------------- host ----------------
extern "C" void kernel_launch(void* const* d_in, const int* in_sizes, int n_in,
                              void* d_out, int out_size, void* d_ws, size_t ws_size,
                              hipStream_t stream)
{
  const float* features = (const float*)d_in[0];
  const int*   reports  = (const int*)d_in[1];
  const float* attn_w1  = (const float*)d_in[2];
  const float* attn_b1  = (const float*)d_in[3];
  const float* attn_w2  = (const float*)d_in[4];
  const float* s_wih    = (const float*)d_in[6];
  const float* s_whh    = (const float*)d_in[7];
  const float* s_bih    = (const float*)d_in[8];
  const float* s_bhh    = (const float*)d_in[9];
  const float* stop_w   = (const float*)d_in[10];
  const float* stop_b   = (const float*)d_in[11];
  const float* emb      = (const float*)d_in[12];
  const float* w_wih    = (const float*)d_in[13];
  const float* w_whh    = (const float*)d_in[14];
  const float* w_bih    = (const float*)d_in[15];
  const float* w_bhh    = (const float*)d_in[16];
  const float* fc_w     = (const float*)d_in[17];
  const float* fc_b     = (const float*)d_in[18];
  float* out = (float*)d_out;
  char*  ws  = (char*)d_ws;
  if (ws_size < WS_TOTAL) return;

  unsigned short* FCWT   = (unsigned short*)(ws + OFF_FCWT);
  unsigned short* WWHHP  = (unsigned short*)(ws + OFF_WWHHP);
  unsigned short* WWIHP  = (unsigned short*)(ws + OFF_WWIHP);
  unsigned short* WSCATP = (unsigned short*)(ws + OFF_WSCATP);
  unsigned short* W1AT   = (unsigned short*)(ws + OFF_W1AT);
  unsigned short* W1BT   = (unsigned short*)(ws + OFF_W1BT);
  unsigned short* FBF    = (unsigned short*)(ws + OFF_FBF);
  unsigned short* XIN    = (unsigned short*)(ws + OFF_XIN);
  float*          PF     = (float*)(ws + OFF_PF);
  float*          XW     = (float*)(ws + OFF_XW);
  unsigned short* HBALL  = (unsigned short*)(ws + OFF_HBALL);
  unsigned short* HW0    = (unsigned short*)(ws + OFF_HWBF0);
  unsigned short* HW1    = (unsigned short*)(ws + OFF_HWBF1);
  unsigned short* ACAT0  = (unsigned short*)(ws + OFF_ACAT0);
  unsigned short* ACAT1  = (unsigned short*)(ws + OFF_ACAT1);
  float*          Hst    = (float*)(ws + OFF_H);
  float*          Cst    = (float*)(ws + OFF_C);
  float*          CW     = (float*)(ws + OFF_CW);
  float*          HPROJ  = (float*)(ws + OFF_HPROJ);
  float*          EVAL   = (float*)(ws + OFF_EVAL);
  unsigned*       BAR    = (unsigned*)(ws + OFF_BAR);

  // mega-prep (grid-stride): conversions, transposes, state + barrier zeroing
  k_prep<<<NPREP, 256, 0, stream>>>(features, w_whh, w_wih, s_wih, s_whh, emb, reports,
                                    attn_w1, fc_w,
                                    FBF, WWHHP, WWIHP, WSCATP, XIN, W1AT, W1BT, FCWT,
                                    ws + ZERO_BASE);

  // PF + XW fused (independent GEMMs co-scheduled; 48KB dynamic LDS)
  k_pf_xw<<<688, 256, 49152, stream>>>(FBF, W1AT, PF, attn_b1, XIN, WWIHP, XW);

  // att0 (HPROJ zeroed by prep)
  k_attn_e<<<784, 256, 0, stream>>>(PF, HPROJ, attn_w2, EVAL);
  k_attn_fin<1><<<16, 256, 0, stream>>>(EVAL, features, Hst, stop_w, stop_b, ACAT0, out, 0);

  // sentence chain: fused gate GEMM+cell (BK=256) -> hproj GEMM -> attn_e -> attn_fin
  unsigned short* ACS[2] = {ACAT0, ACAT1};
  for (int s = 0; s < S_; s++){
    unsigned short* cur = ACS[s & 1];
    unsigned short* nxt = ACS[(s + 1) & 1];
    k_gemm_cell<16,128,256,2,1><<<dim3(32,1), 128, 0, stream>>>(
        cur, 2048, WSCATP, 2048, nullptr, 0, s_bih, s_bhh, Cst,
        nxt + 1024, 2048, HW0 + s*16*1024, Hst, 16, 2048);
    k_gemm<16,64,256,1,4,0><<<dim3(16,1), 256, 0, stream>>>(
        nxt + 1024, 2048, W1BT, 1024, HPROJ, 1024, nullptr, 16, 1024, 1024);
    k_attn_e<<<784, 256, 0, stream>>>(PF, HPROJ, attn_w2, EVAL);
    k_attn_fin<0><<<16, 256, 0, stream>>>(EVAL, features, Hst, stop_w, stop_b, nxt, out, s);
  }

  // word chain: ONE persistent dispatch, 12 steps, load-polling barrier
  k_word_chain<<<dim3(32,5), 128, 0, stream>>>(WWHHP, XW, w_bih, w_bhh, CW, HW0, HW1, HBALL, BAR);

  // fc: single-buffer 64x128 tiles, grid (120,15): 120%8==0 -> n-panel pinned to XCD.
  k_gemm<64,128,64,2,2,2><<<dim3(120,15), 256, 0, stream>>>(HBALL,1024, FCWT,1024, out,V_, fc_b, 960,15000,1024);
}

// Round 18
// 502.516 us; speedup vs baseline: 1.2371x; 1.2371x over previous
//
#include <hip/hip_runtime.h>
#include <hip/hip_bf16.h>

// ---------------- problem constants ----------------
#define B_  16
#define S_  5
#define W_  12
#define NL_ 49
#define H_  1024
#define V_  15000
#define SEQ_N   14400000          // B*S*W*V
#define STOP_N  80
#define OUT_STOP (SEQ_N)
#define OUT_SCORE (SEQ_N + STOP_N)

typedef __attribute__((ext_vector_type(8))) short     short8;
typedef __attribute__((ext_vector_type(4))) float     f32x4;
typedef __attribute__((ext_vector_type(4))) unsigned int u32x4;
typedef __attribute__((ext_vector_type(4))) unsigned short us4;

// ---------------- ws layout (bytes) ----------------
#define OFF_FCWT   0ull            // 15000x1024 bf16
#define OFF_WWHHP  30720000ull     // 4096x1024 bf16 (gate-permuted)
#define OFF_WWIHP  39108608ull     // 4096x1024 bf16 (gate-permuted)
#define OFF_WSCATP 47497216ull     // 4096x2048 bf16 (gate-permuted, wih|whh)
#define OFF_W1AT   64274432ull     // 1024x1024 bf16
#define OFF_W1BT   66371584ull     // 1024x1024 bf16
#define OFF_FBF    68468736ull     // 784x1024 bf16
#define OFF_XIN    70074368ull     // 960x1024 bf16
#define OFF_PF     72040448ull     // 784x1024 f32
#define OFF_XW     75251712ull     // 960x4096 f32 (cols gate-permuted)
#define OFF_HBALL  90980352ull     // 960x1024 bf16
#define OFF_HWBF0  92946432ull     // 80x1024 bf16
#define OFF_HWBF1  93110272ull     // 80x1024 bf16
#define OFF_ACAT1  93274112ull     // 16x2048 bf16
#define OFF_H      93339648ull     // 16x1024 f32
#define OFF_EVAL   93405184ull     // 784 f32
#define OFF_ACAT0  93408384ull     // 16x2048 bf16   -- zero region start
#define OFF_C      93473920ull     // 16x1024 f32
#define OFF_CW     93539456ull     // 80x1024 f32
#define OFF_HPROJ  93867136ull     // 16x1024 f32
#define WS_TOTAL   93932672ull
#define ZERO_BASE  OFF_ACAT0
#define ZERO_BYTES (524288ull)

// ---------------- helpers ----------------
__device__ __forceinline__ unsigned short f2bf(float x){
  unsigned u = __float_as_uint(x);
  u += 0x7fffu + ((u >> 16) & 1u);
  return (unsigned short)(u >> 16);
}
__device__ __forceinline__ float sigm(float x){ return 1.f/(1.f+expf(-x)); }

typedef __attribute__((address_space(3))) unsigned int  as3_u32;
typedef __attribute__((address_space(1))) const unsigned int as1_u32;

__device__ __forceinline__ void gl16(const void* g, void* l){
  __builtin_amdgcn_global_load_lds((as1_u32*)g, (as3_u32*)l, 16, 0, 0);
}

// Stage ROWS x (CH*8) bf16 tile into LDS via global_load_lds, XOR-swizzled SOURCE
// so LDS slot [r][cb'] holds global chunk cb'^(r&7).
template<int ROWS,int CH,int NW>
__device__ __forceinline__ void stage_swz(const unsigned short* __restrict__ gbase, int grs,
                                          unsigned short* lds, int wid, int lane,
                                          int r0, int rmax){
  constexpr int RPI = 64/CH;
  constexpr int NISS = ROWS/RPI;
  const int r_in = lane / CH;
  const int cbp  = lane % CH;
  #pragma unroll
  for (int it = wid; it < NISS; it += NW){
    int rl = it*RPI + r_in;
    int gr = r0 + rl; gr = gr < rmax ? gr : rmax-1;
    int cb = cbp ^ (rl & 7);
    gl16(gbase + (size_t)gr*grs + cb*8, lds + it*RPI*CH*8);
  }
}

// ---------------- coalesced 64x64 f32->bf16 transpose tile ----------------
__device__ __forceinline__ void transp64(const float* __restrict__ src, int sld,
                                         int rb, int cb, int Cc,
                                         unsigned short* __restrict__ dst, int dld,
                                         float (*t)[65])
{
  const int tx = threadIdx.x & 15, ty = threadIdx.x >> 4;
  #pragma unroll
  for (int ii = 0; ii < 4; ii++){
    int r = ty + ii*16;
    int c = cb + tx*4;
    const float* s = src + (size_t)(rb + r)*sld + c;
    f32x4 v;
    if (c + 4 <= Cc) v = *(const f32x4*)s;
    else {
      v[0] = (c   < Cc) ? s[0] : 0.f;
      v[1] = (c+1 < Cc) ? s[1] : 0.f;
      v[2] = (c+2 < Cc) ? s[2] : 0.f;
      v[3] = (c+3 < Cc) ? s[3] : 0.f;
    }
    t[r][tx*4+0]=v[0]; t[r][tx*4+1]=v[1]; t[r][tx*4+2]=v[2]; t[r][tx*4+3]=v[3];
  }
  __syncthreads();
  #pragma unroll
  for (int ii = 0; ii < 4; ii++){
    int c = ty + ii*16;
    if (cb + c < Cc){
      int r4 = tx*4;
      us4 o; o[0]=f2bf(t[r4][c]); o[1]=f2bf(t[r4+1][c]); o[2]=f2bf(t[r4+2][c]); o[3]=f2bf(t[r4+3][c]);
      *(us4*)(dst + (size_t)(cb + c)*dld + rb + r4) = o;
    }
  }
}

// ---------------- mega-prep (grid-stride) ----------------
#define U0 200704u                 // features units (784*256)
#define U1 (U0+1048576u)           // w_whh
#define U2 (U1+1048576u)           // w_wih
#define U3 (U2+1048576u)           // s_wih
#define U4 (U3+1048576u)           // s_whh
#define U5 (U4+245760u)            // gather  (total units)
#define NCVT_BLK 1280
#define NTR_BLK  2136              // x2 tiles = 4272 = 512 attn + 3760 fc
#define NZ_BLK   16
#define NPREP    (NCVT_BLK + NTR_BLK + NZ_BLK)

__device__ __forceinline__ void cvt_gate_unit(const float* __restrict__ src,
                                              unsigned short* __restrict__ dst,
                                              unsigned e, int dld, int doff){
  int n = e >> 8, cc = (e & 255)*4;
  int gate = (n >> 4) & 3, j = ((n >> 6) << 4) | (n & 15);
  f32x4 v = *(const f32x4*)(src + ((size_t)(gate*1024 + j) << 10) + cc);
  us4 o; o[0]=f2bf(v[0]); o[1]=f2bf(v[1]); o[2]=f2bf(v[2]); o[3]=f2bf(v[3]);
  *(us4*)(dst + (size_t)n*dld + doff + cc) = o;
}

__global__ void k_prep(const float* __restrict__ features,
                       const float* __restrict__ w_whh, const float* __restrict__ w_wih,
                       const float* __restrict__ s_wih, const float* __restrict__ s_whh,
                       const float* __restrict__ emb, const int* __restrict__ reports,
                       const float* __restrict__ attn_w1, const float* __restrict__ fc_w,
                       unsigned short* __restrict__ FBF, unsigned short* __restrict__ WWHHP,
                       unsigned short* __restrict__ WWIHP, unsigned short* __restrict__ WSCATP,
                       unsigned short* __restrict__ XIN,
                       unsigned short* __restrict__ W1AT, unsigned short* __restrict__ W1BT,
                       unsigned short* __restrict__ FCWT, char* __restrict__ zbase)
{
  __shared__ float t[64][65];
  int bx = blockIdx.x;
  if (bx < NCVT_BLK){
    for (unsigned u = bx*256u + threadIdx.x; u < U5; u += NCVT_BLK*256u){
      if (u < U0){
        int idx = u*4;
        f32x4 v = *(const f32x4*)(features + idx);
        us4 o; o[0]=f2bf(v[0]); o[1]=f2bf(v[1]); o[2]=f2bf(v[2]); o[3]=f2bf(v[3]);
        *(us4*)(FBF + idx) = o;
      } else if (u < U1){
        cvt_gate_unit(w_whh, WWHHP, u - U0, 1024, 0);
      } else if (u < U2){
        cvt_gate_unit(w_wih, WWIHP, u - U1, 1024, 0);
      } else if (u < U3){
        cvt_gate_unit(s_wih, WSCATP, u - U2, 2048, 0);
      } else if (u < U4){
        cvt_gate_unit(s_whh, WSCATP, u - U3, 2048, 1024);
      } else {
        unsigned e = u - U4;
        int m = e >> 8, k = (e & 255)*4;
        int w = m / 80, r = m % 80, s = r >> 4, b = r & 15;
        int tok = (w == 0) ? 1 : reports[b*60 + s*12 + (w-1)];
        f32x4 v = *(const f32x4*)(emb + ((size_t)tok << 10) + k);
        us4 o; o[0]=f2bf(v[0]); o[1]=f2bf(v[1]); o[2]=f2bf(v[2]); o[3]=f2bf(v[3]);
        *(us4*)(XIN + (size_t)m*1024 + k) = o;
      }
    }
  } else if (bx < NCVT_BLK + NTR_BLK){
    int base = (bx - NCVT_BLK)*2;
    #pragma unroll
    for (int bt = 0; bt < 2; bt++){
      if (bt) __syncthreads();
      int tile = base + bt;
      if (tile < 512){
        int z = tile >> 8, rem = tile & 255;
        int rb = (rem & 15)*64, cb = (rem >> 4)*64;
        transp64(attn_w1 + (size_t)z*1024*1024, 1024, rb, cb, 1024, z ? W1BT : W1AT, 1024, t);
      } else {
        int ft = tile - 512;
        int rb = (ft & 15)*64, cb = (ft >> 4)*64;
        transp64(fc_w, V_, rb, cb, V_, FCWT, 1024, t);
      }
    }
  } else {
    int idx = bx - (NCVT_BLK + NTR_BLK);
    #pragma unroll
    for (int it = 0; it < 8; it++){
      size_t off = ((size_t)(idx + it*NZ_BLK))*4096 + threadIdx.x*16;
      *(u32x4*)(zbase + off) = (u32x4){0u,0u,0u,0u};
    }
  }
}

// ---------------- GEMM core (LDS pointers passed in) ----------------
// EPI: 0 plain, 1 +bias, 2 +bias & scatter rows to seq output (nt), 3 plain nt
template<int BM,int BN,int BK,int WM,int WN,int EPI>
__device__ __forceinline__ void gemm_core(
    unsigned short* As, unsigned short* Bs,
    const unsigned short* __restrict__ A, int lda,
    const unsigned short* __restrict__ Bt, int ldb,
    float* __restrict__ C, int ldc,
    const float* __restrict__ bias,
    int M, int N, int K, int n0, int m0)
{
  constexpr int NWV = WM*WN;
  constexpr int CH = BK/8;
  const int tid  = threadIdx.x;
  const int lane = tid & 63;
  const int wave = tid >> 6;
  constexpr int WROWS = BM/WM, WCOLS = BN/WN;
  constexpr int FM = WROWS/16, FN = WCOLS/16;
  const int wm = wave / WN, wn = wave % WN;
  const int g = lane >> 4, fr = lane & 15;
  const int sx = fr & 7;

  f32x4 acc[FM][FN];
  #pragma unroll
  for (int a=0;a<FM;a++)
    #pragma unroll
    for (int b=0;b<FN;b++) acc[a][b] = (f32x4){0.f,0.f,0.f,0.f};

  for (int k0 = 0; k0 < K; k0 += BK) {
    if (k0) __syncthreads();
    stage_swz<BM,CH,NWV>(A + k0, lda, As, wave, lane, m0, M);
    stage_swz<BN,CH,NWV>(Bt + k0, ldb, Bs, wave, lane, n0, N);
    __syncthreads();
    #pragma unroll
    for (int kk = 0; kk < BK; kk += 32) {
      const int so = ((kk/8 + g) ^ sx) * 8;
      short8 af[FM], bt[FN];
      #pragma unroll
      for (int fm=0; fm<FM; fm++)
        af[fm] = *(const short8*)(As + (wm*WROWS + fm*16 + fr)*BK + so);
      #pragma unroll
      for (int fn=0; fn<FN; fn++)
        bt[fn] = *(const short8*)(Bs + (wn*WCOLS + fn*16 + fr)*BK + so);
      #pragma unroll
      for (int fm=0; fm<FM; fm++)
        #pragma unroll
        for (int fn=0; fn<FN; fn++)
          acc[fm][fn] = __builtin_amdgcn_mfma_f32_16x16x32_bf16(af[fm], bt[fn], acc[fm][fn], 0, 0, 0);
    }
  }

  #pragma unroll
  for (int fm=0; fm<FM; fm++)
    #pragma unroll
    for (int fn=0; fn<FN; fn++)
      #pragma unroll
      for (int j=0; j<4; j++){
        int m = m0 + wm*WROWS + fm*16 + g*4 + j;
        int n = n0 + wn*WCOLS + fn*16 + fr;
        if (m < M && n < N) {
          float v = acc[fm][fn][j];
          if (EPI == 1 || EPI == 2) v += bias[n];
          if (EPI == 2) {
            int b = m & 15, s = (m >> 4) % 5, w = m / 80;
            __builtin_nontemporal_store(v, &C[(size_t)((b*5 + s)*12 + w)*V_ + n]);
          } else if (EPI == 3) {
            __builtin_nontemporal_store(v, &C[(size_t)m*ldc + n]);
          } else {
            C[(size_t)m*ldc + n] = v;
          }
        }
      }
}

// standalone GEMM (static LDS)
template<int BM,int BN,int BK,int WM,int WN,int EPI>
__global__ void k_gemm(const unsigned short* __restrict__ A, int lda,
                       const unsigned short* __restrict__ Bt, int ldb,
                       float* __restrict__ C, int ldc,
                       const float* __restrict__ bias,
                       int M, int N, int K)
{
  __shared__ __align__(16) unsigned short As[BM*BK];
  __shared__ __align__(16) unsigned short Bs[BN*BK];
  const int n0 = blockIdx.x * BN, m0 = blockIdx.y * BM;
  if (n0 >= N) return;
  gemm_core<BM,BN,BK,WM,WN,EPI>(As, Bs, A, lda, Bt, ldb, C, ldc, bias, M, N, K, n0, m0);
}

// fused PF + XW GEMMs (independent) in one dispatch; 48KB dynamic LDS (union)
__global__ void __launch_bounds__(256) k_pf_xw(
    const unsigned short* __restrict__ FBF, const unsigned short* __restrict__ W1AT,
    float* __restrict__ PF, const float* __restrict__ attn_b1,
    const unsigned short* __restrict__ XIN, const unsigned short* __restrict__ WWIHP,
    float* __restrict__ XW)
{
  extern __shared__ __align__(16) unsigned short smem[];
  unsigned short* As = smem;
  unsigned short* Bs = smem + 64*128;       // 16KB for As (both variants)
  int bx = blockIdx.x;
  if (bx < 208){
    int n0 = (bx & 15)*64, m0 = (bx >> 4)*64;
    gemm_core<64,64,128,2,2,1>(As, Bs, FBF,1024, W1AT,1024, PF,1024, attn_b1,
                               784,1024,1024, n0, m0);
  } else {
    int t = bx - 208;
    int n0 = (t & 31)*128, m0 = (t >> 5)*64;
    gemm_core<64,128,128,2,2,3>(As, Bs, XIN,1024, WWIHP,1024, XW,4096, nullptr,
                                960,4096,1024, n0, m0);
  }
}

// ---------------- gate GEMM fused with LSTM cell (single-buffer, BK templated) ----------------
template<int BM,int BN,int BK,int WN,int SENT>
__global__ void k_gemm_cell(const unsigned short* __restrict__ A, int lda,
                            const unsigned short* __restrict__ Bt, int ldb,
                            const float* __restrict__ Xg, int ldx,
                            const float* __restrict__ bih, const float* __restrict__ bhh,
                            float* __restrict__ cst,
                            unsigned short* __restrict__ h1, int ldh1,
                            unsigned short* __restrict__ h2,
                            float* __restrict__ hf,
                            int M, int K)
{
  constexpr int CH = BK/8;
  __shared__ __align__(16) unsigned short As[BM*BK];
  __shared__ __align__(16) unsigned short Bs[BN*BK];
  const int tid  = threadIdx.x;
  const int lane = tid & 63;
  const int wn   = tid >> 6;
  const int n0 = blockIdx.x * BN, m0 = blockIdx.y * BM;
  const int g = lane >> 4, fr = lane & 15;
  const int sx = fr & 7;

  f32x4 acc[4];
  #pragma unroll
  for (int b=0;b<4;b++) acc[b] = (f32x4){0.f,0.f,0.f,0.f};

  for (int k0 = 0; k0 < K; k0 += BK) {
    if (k0) __syncthreads();
    stage_swz<BM,CH,WN>(A + k0, lda, As, wn, lane, m0, M);
    stage_swz<BN,CH,WN>(Bt + k0, ldb, Bs, wn, lane, n0, 4096);
    __syncthreads();
    #pragma unroll
    for (int kk = 0; kk < BK; kk += 32) {
      const int so = ((kk/8 + g) ^ sx) * 8;
      short8 af = *(const short8*)(As + fr*BK + so);
      #pragma unroll
      for (int fn=0; fn<4; fn++){
        short8 bt = *(const short8*)(Bs + (wn*64 + fn*16 + fr)*BK + so);
        acc[fn] = __builtin_amdgcn_mfma_f32_16x16x32_bf16(af, bt, acc[fn], 0, 0, 0);
      }
    }
  }

  const int nb = n0 + wn*64 + fr;       // column of gate 0 (permuted layout)
  const int j  = ((n0 + wn*64) >> 2) + fr;
  const float b0 = bih[j]        + bhh[j];
  const float b1 = bih[1024 + j] + bhh[1024 + j];
  const float b2 = bih[2048 + j] + bhh[2048 + j];
  const float b3 = bih[3072 + j] + bhh[3072 + j];
  #pragma unroll
  for (int jj=0; jj<4; jj++){
    int m = m0 + g*4 + jj;
    if (m < M){
      float gi = acc[0][jj] + b0;
      float gf = acc[1][jj] + b1;
      float gg = acc[2][jj] + b2;
      float go = acc[3][jj] + b3;
      if (!SENT){
        const float* xg = Xg + (size_t)m*ldx + nb;
        gi += xg[0]; gf += xg[16]; gg += xg[32]; go += xg[48];
      }
      float cn = sigm(gf)*cst[m*1024 + j] + sigm(gi)*tanhf(gg);
      float hn = sigm(go)*tanhf(cn);
      cst[m*1024 + j] = cn;
      unsigned short hb = f2bf(hn);
      h1[(size_t)m*ldh1 + j] = hb;
      h2[(size_t)m*1024 + j] = hb;
      if (SENT) hf[m*1024 + j] = hn;
    }
  }
}

// ---------------- attention (wide): evals then softmax/sum/stop ----------------
__global__ void k_attn_e(const float* __restrict__ PF, const float* __restrict__ hproj,
                         const float* __restrict__ w2, float* __restrict__ evals)
{
  const int bn = blockIdx.x;
  const int b  = bn / NL_;
  const int tid = threadIdx.x;
  __shared__ float red[4];
  const float* pf = PF + ((size_t)bn << 10);
  const float* hp = hproj + (b << 10);
  int k = tid * 4;
  f32x4 a = *(const f32x4*)(pf + k);
  f32x4 hh = *(const f32x4*)(hp + k);
  f32x4 w = *(const f32x4*)(w2 + k);
  float p = tanhf(a[0]+hh[0])*w[0] + tanhf(a[1]+hh[1])*w[1]
          + tanhf(a[2]+hh[2])*w[2] + tanhf(a[3]+hh[3])*w[3];
  #pragma unroll
  for (int o = 32; o; o >>= 1) p += __shfl_down(p, o, 64);
  if ((tid & 63) == 0) red[tid >> 6] = p;
  __syncthreads();
  if (tid == 0) evals[bn] = red[0] + red[1] + red[2] + red[3];
}

template<int INIT>
__global__ void k_attn_fin(const float* __restrict__ evals, const float* __restrict__ features,
                           const float* __restrict__ h, const float* __restrict__ stop_w,
                           const float* __restrict__ stop_b,
                           unsigned short* __restrict__ Acat, float* __restrict__ outp, int s)
{
  const int b = blockIdx.x, tid = threadIdx.x;
  __shared__ float scs[64];
  __shared__ float red[4];
  if (tid < 64){
    float e = (tid < NL_) ? evals[b*NL_ + tid] : -1e30f;
    float mx = e;
    #pragma unroll
    for (int o = 32; o; o >>= 1) mx = fmaxf(mx, __shfl_xor(mx, o, 64));
    float ex = (tid < NL_) ? expf(e - mx) : 0.f;
    float dn = ex;
    #pragma unroll
    for (int o = 32; o; o >>= 1) dn += __shfl_xor(dn, o, 64);
    float sc = ex / dn;
    if (tid < NL_){
      scs[tid] = sc;
      if (!INIT) outp[OUT_SCORE + (b*5 + s)*NL_ + tid] = sc;
    }
  }
  __syncthreads();
  {
    int f0 = tid * 4;
    f32x4 a = (f32x4){0.f,0.f,0.f,0.f};
    const float* fb = features + (((size_t)b*NL_) << 10) + f0;
    #pragma unroll 7
    for (int n = 0; n < NL_; n++){
      f32x4 v = *(const f32x4*)(fb + ((size_t)n << 10));
      float sc = scs[n];
      a[0] += sc*v[0]; a[1] += sc*v[1]; a[2] += sc*v[2]; a[3] += sc*v[3];
    }
    us4 o4; o4[0]=f2bf(a[0]); o4[1]=f2bf(a[1]); o4[2]=f2bf(a[2]); o4[3]=f2bf(a[3]);
    *(us4*)(Acat + b*2048 + f0) = o4;
  }
  if (!INIT){
    int k = tid * 4;
    f32x4 hv = *(const f32x4*)(h + (b << 10) + k);
    f32x4 sw = *(const f32x4*)(stop_w + k);
    float p = hv[0]*sw[0] + hv[1]*sw[1] + hv[2]*sw[2] + hv[3]*sw[3];
    #pragma unroll
    for (int o = 32; o; o >>= 1) p += __shfl_down(p, o, 64);
    if ((tid & 63) == 0) red[tid >> 6] = p;
    __syncthreads();
    if (tid == 0) outp[OUT_STOP + b*5 + s] = sigm(red[0]+red[1]+red[2]+red[3] + stop_b[0]);
  }
}

// ---------------- host ----------------
extern "C" void kernel_launch(void* const* d_in, const int* in_sizes, int n_in,
                              void* d_out, int out_size, void* d_ws, size_t ws_size,
                              hipStream_t stream)
{
  const float* features = (const float*)d_in[0];
  const int*   reports  = (const int*)d_in[1];
  const float* attn_w1  = (const float*)d_in[2];
  const float* attn_b1  = (const float*)d_in[3];
  const float* attn_w2  = (const float*)d_in[4];
  const float* s_wih    = (const float*)d_in[6];
  const float* s_whh    = (const float*)d_in[7];
  const float* s_bih    = (const float*)d_in[8];
  const float* s_bhh    = (const float*)d_in[9];
  const float* stop_w   = (const float*)d_in[10];
  const float* stop_b   = (const float*)d_in[11];
  const float* emb      = (const float*)d_in[12];
  const float* w_wih    = (const float*)d_in[13];
  const float* w_whh    = (const float*)d_in[14];
  const float* w_bih    = (const float*)d_in[15];
  const float* w_bhh    = (const float*)d_in[16];
  const float* fc_w     = (const float*)d_in[17];
  const float* fc_b     = (const float*)d_in[18];
  float* out = (float*)d_out;
  char*  ws  = (char*)d_ws;
  if (ws_size < WS_TOTAL) return;

  unsigned short* FCWT   = (unsigned short*)(ws + OFF_FCWT);
  unsigned short* WWHHP  = (unsigned short*)(ws + OFF_WWHHP);
  unsigned short* WWIHP  = (unsigned short*)(ws + OFF_WWIHP);
  unsigned short* WSCATP = (unsigned short*)(ws + OFF_WSCATP);
  unsigned short* W1AT   = (unsigned short*)(ws + OFF_W1AT);
  unsigned short* W1BT   = (unsigned short*)(ws + OFF_W1BT);
  unsigned short* FBF    = (unsigned short*)(ws + OFF_FBF);
  unsigned short* XIN    = (unsigned short*)(ws + OFF_XIN);
  float*          PF     = (float*)(ws + OFF_PF);
  float*          XW     = (float*)(ws + OFF_XW);
  unsigned short* HBALL  = (unsigned short*)(ws + OFF_HBALL);
  unsigned short* HW0    = (unsigned short*)(ws + OFF_HWBF0);
  unsigned short* HW1    = (unsigned short*)(ws + OFF_HWBF1);
  unsigned short* ACAT0  = (unsigned short*)(ws + OFF_ACAT0);
  unsigned short* ACAT1  = (unsigned short*)(ws + OFF_ACAT1);
  float*          Hst    = (float*)(ws + OFF_H);
  float*          Cst    = (float*)(ws + OFF_C);
  float*          CW     = (float*)(ws + OFF_CW);
  float*          HPROJ  = (float*)(ws + OFF_HPROJ);
  float*          EVAL   = (float*)(ws + OFF_EVAL);

  // mega-prep (grid-stride): all conversions, both transposes, state zeroing
  k_prep<<<NPREP, 256, 0, stream>>>(features, w_whh, w_wih, s_wih, s_whh, emb, reports,
                                    attn_w1, fc_w,
                                    FBF, WWHHP, WWIHP, WSCATP, XIN, W1AT, W1BT, FCWT,
                                    ws + ZERO_BASE);

  // PF + XW fused (independent GEMMs co-scheduled; 48KB dynamic LDS)
  k_pf_xw<<<688, 256, 49152, stream>>>(FBF, W1AT, PF, attn_b1, XIN, WWIHP, XW);

  // att0 (HPROJ zeroed by prep)
  k_attn_e<<<784, 256, 0, stream>>>(PF, HPROJ, attn_w2, EVAL);
  k_attn_fin<1><<<16, 256, 0, stream>>>(EVAL, features, Hst, stop_w, stop_b, ACAT0, out, 0);

  // sentence chain: fused gate GEMM+cell (BK=256) -> hproj GEMM -> attn_e -> attn_fin
  unsigned short* ACS[2] = {ACAT0, ACAT1};
  for (int s = 0; s < S_; s++){
    unsigned short* cur = ACS[s & 1];
    unsigned short* nxt = ACS[(s + 1) & 1];
    k_gemm_cell<16,128,256,2,1><<<dim3(32,1), 128, 0, stream>>>(
        cur, 2048, WSCATP, 2048, nullptr, 0, s_bih, s_bhh, Cst,
        nxt + 1024, 2048, HW0 + s*16*1024, Hst, 16, 2048);
    k_gemm<16,64,256,1,4,0><<<dim3(16,1), 256, 0, stream>>>(
        nxt + 1024, 2048, W1BT, 1024, HPROJ, 1024, nullptr, 16, 1024, 1024);
    k_attn_e<<<784, 256, 0, stream>>>(PF, HPROJ, attn_w2, EVAL);
    k_attn_fin<0><<<16, 256, 0, stream>>>(EVAL, features, Hst, stop_w, stop_b, nxt, out, s);
  }

  // word chain: 12 steps (double-buffered h), BK=256 -> 4 K-iterations per step
  unsigned short* HW[2] = {HW0, HW1};
  for (int w = 0; w < W_; w++){
    k_gemm_cell<16,128,256,2,0><<<dim3(32,5), 128, 0, stream>>>(
        HW[w & 1], 1024, WWHHP, 1024, XW + (size_t)w*80*4096, 4096, w_bih, w_bhh, CW,
        HW[(w + 1) & 1], 1024, HBALL + (size_t)w*80*1024, nullptr, 80, 1024);
  }

  // fc: single-buffer 64x128 tiles, grid (120,15): 120%8==0 -> n-panel pinned to XCD.
  k_gemm<64,128,64,2,2,2><<<dim3(120,15), 256, 0, stream>>>(HBALL,1024, FCWT,1024, out,V_, fc_b, 960,15000,1024);
}